// Round 1
// baseline (236.657 us; speedup 1.0000x reference)
//
#include <hip/hip_runtime.h>

#define TPB 256
#define NWAVE (TPB / 64)

struct SegInfo {
    int gb, ga, gt, gi;           // cumulative block-range ends: bond, angle, torsion, inversion
    int NB, NA, NT, NI, NC;
    int N;
};

__device__ __forceinline__ float clamp1(float x) {
    return fminf(fmaxf(x, -0.999999f), 0.999999f);
}

// Load 4 consecutive batch replicas (half h: batches 4h..4h+3) of one atom.
// USE_WS: packed layout float4[atom][8] (128B/atom, one cache line).
// else  : native coords (B, N, 3) strided loads.
template <bool USE_WS>
__device__ __forceinline__ void load4(const float4* __restrict__ cw,
                                      const float* __restrict__ coords,
                                      int N, int atom, int h, float4 v[4]) {
    if (USE_WS) {
        const float4* p = cw + ((size_t)atom << 3) + (h << 2);
#pragma unroll
        for (int j = 0; j < 4; j++) v[j] = p[j];
    } else {
#pragma unroll
        for (int j = 0; j < 4; j++) {
            const float* sp = coords + ((size_t)(h * 4 + j) * N + atom) * 3;
            v[j] = make_float4(sp[0], sp[1], sp[2], 0.f);
        }
    }
}

// Repack coords (B,N,3) -> ws float4[atom][8] so one atom's 8 replicas share a 128B line.
__global__ void __launch_bounds__(TPB) transpose_coords(const float* __restrict__ coords,
                                                        float4* __restrict__ cw, int N) {
    int a = blockIdx.x * TPB + threadIdx.x;
    if (a >= N) return;
#pragma unroll
    for (int b = 0; b < 8; b++) {
        const float* s = coords + ((size_t)b * N + a) * 3;
        cw[((size_t)a << 3) + b] = make_float4(s[0], s[1], s[2], 0.f);
    }
}

template <bool USE_WS>
__global__ void __launch_bounds__(TPB) uff_kernel(
    const float* __restrict__ coords, const float4* __restrict__ cw,
    const int* __restrict__ bidx, const float* __restrict__ br0, const float* __restrict__ bk,
    const int* __restrict__ aidx, const float* __restrict__ ak,
    const float* __restrict__ ac0, const float* __restrict__ ac1, const float* __restrict__ ac2,
    const int* __restrict__ tidx, const float* __restrict__ tk,
    const int* __restrict__ tord, const float* __restrict__ tcos,
    const int* __restrict__ iidx, const float* __restrict__ ik,
    const float* __restrict__ ic0, const float* __restrict__ ic1, const float* __restrict__ ic2,
    const int* __restrict__ nidx, const float* __restrict__ vmin,
    const float* __restrict__ vdep, const float* __restrict__ vthr,
    float* __restrict__ out, SegInfo s)
{
    float acc[8];
#pragma unroll
    for (int b = 0; b < 8; b++) acc[b] = 0.f;

    const int blk = blockIdx.x;
    const int tid = threadIdx.x;
    const int N = s.N;

    if (blk < s.gb) {
        // ---------------- bond stretch ----------------
        const int t = blk * TPB + tid;
        if (t < s.NB) {
            const int2 ij = ((const int2*)bidx)[t];
            const float r0 = br0[t], k = bk[t];
#pragma unroll
            for (int h = 0; h < 2; h++) {
                float4 ci[4], cj[4];
                load4<USE_WS>(cw, coords, N, ij.x, h, ci);
                load4<USE_WS>(cw, coords, N, ij.y, h, cj);
#pragma unroll
                for (int j = 0; j < 4; j++) {
                    float dx = ci[j].x - cj[j].x, dy = ci[j].y - cj[j].y, dz = ci[j].z - cj[j].z;
                    float dist = sqrtf(dx * dx + dy * dy + dz * dz);
                    float dd = dist - r0;
                    acc[h * 4 + j] += 0.5f * k * dd * dd;
                }
            }
        }
    } else if (blk < s.ga) {
        // ---------------- angle bend ----------------
        const int t = (blk - s.gb) * TPB + tid;
        if (t < s.NA) {
            const int i1 = aidx[3 * t], i2 = aidx[3 * t + 1], i3 = aidx[3 * t + 2];
            const float k = ak[t], c0 = ac0[t], c1 = ac1[t], c2 = ac2[t];
#pragma unroll
            for (int h = 0; h < 2; h++) {
                float4 P[4], Q[4], R[4];
                load4<USE_WS>(cw, coords, N, i1, h, P);
                load4<USE_WS>(cw, coords, N, i2, h, Q);
                load4<USE_WS>(cw, coords, N, i3, h, R);
#pragma unroll
                for (int j = 0; j < 4; j++) {
                    float ax = P[j].x - Q[j].x, ay = P[j].y - Q[j].y, az = P[j].z - Q[j].z;
                    float bx = R[j].x - Q[j].x, by = R[j].y - Q[j].y, bz = R[j].z - Q[j].z;
                    float dot = ax * bx + ay * by + az * bz;
                    float nn = (ax * ax + ay * ay + az * az) * (bx * bx + by * by + bz * bz);
                    float ct = clamp1(dot * rsqrtf(fmaxf(nn, 1e-24f)));
                    float cs = ct * ct;
                    float ss = fmaxf(1.f - cs, 1e-12f);
                    acc[h * 4 + j] += k * (c0 + c1 * ct + c2 * (cs - ss));
                }
            }
        }
    } else if (blk < s.gt) {
        // ---------------- torsion ----------------
        const int t = (blk - s.ga) * TPB + tid;
        if (t < s.NT) {
            const int4 q = ((const int4*)tidx)[t];
            const float V = tk[t], ctm = tcos[t];
            const int ord = tord[t];
#pragma unroll
            for (int h = 0; h < 2; h++) {
                float4 P[4], Q[4];
                load4<USE_WS>(cw, coords, N, q.x, h, P);
                load4<USE_WS>(cw, coords, N, q.y, h, Q);
                float b1x[4], b1y[4], b1z[4];
#pragma unroll
                for (int j = 0; j < 4; j++) {
                    b1x[j] = Q[j].x - P[j].x; b1y[j] = Q[j].y - P[j].y; b1z[j] = Q[j].z - P[j].z;
                }
                load4<USE_WS>(cw, coords, N, q.z, h, P);  // P = atom3
                float b2x[4], b2y[4], b2z[4];
#pragma unroll
                for (int j = 0; j < 4; j++) {
                    b2x[j] = P[j].x - Q[j].x; b2y[j] = P[j].y - Q[j].y; b2z[j] = P[j].z - Q[j].z;
                }
                load4<USE_WS>(cw, coords, N, q.w, h, Q);  // Q = atom4
#pragma unroll
                for (int j = 0; j < 4; j++) {
                    float b3x = Q[j].x - P[j].x, b3y = Q[j].y - P[j].y, b3z = Q[j].z - P[j].z;
                    float n1x = b1y[j] * b2z[j] - b1z[j] * b2y[j];
                    float n1y = b1z[j] * b2x[j] - b1x[j] * b2z[j];
                    float n1z = b1x[j] * b2y[j] - b1y[j] * b2x[j];
                    float n2x = b2y[j] * b3z - b2z[j] * b3y;
                    float n2y = b2z[j] * b3x - b2x[j] * b3z;
                    float n2z = b2x[j] * b3y - b2y[j] * b3x;
                    float dot = n1x * n2x + n1y * n2y + n1z * n2z;
                    float nn = (n1x * n1x + n1y * n1y + n1z * n1z) *
                               (n2x * n2x + n2y * n2y + n2z * n2z);
                    float x = clamp1(dot * rsqrtf(fmaxf(nn, 1e-24f)));
                    // cos(n*acos(x)) = T_n(x), n in [1,6]
                    float Tp = 1.f, Tc = x, res = x;
#pragma unroll
                    for (int kk = 2; kk <= 6; kk++) {
                        float Tn = 2.f * x * Tc - Tp;
                        Tp = Tc; Tc = Tn;
                        if (ord == kk) res = Tn;
                    }
                    acc[h * 4 + j] += 0.5f * V * (1.f - ctm * res);
                }
            }
        }
    } else if (blk < s.gi) {
        // ---------------- inversion (Wilson) ----------------
        const int t = (blk - s.gt) * TPB + tid;
        if (t < s.NI) {
            const int4 q = ((const int4*)iidx)[t];  // cols: i, central, k, l
            const float K = ik[t], c0 = ic0[t], c1 = ic1[t], c2 = ic2[t];
#pragma unroll
            for (int h = 0; h < 2; h++) {
                float4 CA[4], P[4];
                load4<USE_WS>(cw, coords, N, q.y, h, CA);
                load4<USE_WS>(cw, coords, N, q.x, h, P);
                float jix[4], jiy[4], jiz[4];
#pragma unroll
                for (int j = 0; j < 4; j++) {
                    jix[j] = P[j].x - CA[j].x; jiy[j] = P[j].y - CA[j].y; jiz[j] = P[j].z - CA[j].z;
                }
                load4<USE_WS>(cw, coords, N, q.z, h, P);
                float jkx[4], jky[4], jkz[4];
#pragma unroll
                for (int j = 0; j < 4; j++) {
                    jkx[j] = P[j].x - CA[j].x; jky[j] = P[j].y - CA[j].y; jkz[j] = P[j].z - CA[j].z;
                }
                load4<USE_WS>(cw, coords, N, q.w, h, P);
#pragma unroll
                for (int j = 0; j < 4; j++) {
                    float lx = P[j].x - CA[j].x, ly = P[j].y - CA[j].y, lz = P[j].z - CA[j].z;
                    float nx = jiy[j] * jkz[j] - jiz[j] * jky[j];
                    float ny = jiz[j] * jkx[j] - jix[j] * jkz[j];
                    float nz = jix[j] * jky[j] - jiy[j] * jkx[j];
                    float dot = nx * lx + ny * ly + nz * lz;
                    float nn = (nx * nx + ny * ny + nz * nz) * (lx * lx + ly * ly + lz * lz);
                    float cosY = clamp1(dot * rsqrtf(fmaxf(nn, 1e-24f)));
                    float sinY = sqrtf(fmaxf(1.f - cosY * cosY, 0.f));
                    acc[h * 4 + j] += K * (c0 + c1 * sinY + c2 * (2.f * sinY * sinY - 1.f));
                }
            }
        }
    } else {
        // ---------------- vdW LJ ----------------
        const int t = (blk - s.gi) * TPB + tid;
        if (t < s.NC) {
            const int2 ij = ((const int2*)nidx)[t];
            const float R = vmin[t], D = vdep[t], thr = vthr[t];
            const float R2 = R * R;
#pragma unroll
            for (int h = 0; h < 2; h++) {
                float4 ci[4], cj[4];
                load4<USE_WS>(cw, coords, N, ij.x, h, ci);
                load4<USE_WS>(cw, coords, N, ij.y, h, cj);
#pragma unroll
                for (int j = 0; j < 4; j++) {
                    float dx = ci[j].x - cj[j].x, dy = ci[j].y - cj[j].y, dz = ci[j].z - cj[j].z;
                    float d2 = dx * dx + dy * dy + dz * dz;
                    float x2 = R2 / fmaxf(d2, 1e-12f);
                    float x6 = x2 * x2 * x2;
                    float e = D * (x6 * x6 - 2.f * x6);
                    if (d2 <= thr) acc[h * 4 + j] += e;
                }
            }
        }
    }

    // ---------------- block reduction: 8 batch sums ----------------
    __shared__ float red[NWAVE][8];
    const int lane = tid & 63;
    const int wid = tid >> 6;
#pragma unroll
    for (int b = 0; b < 8; b++) {
        float v = acc[b];
#pragma unroll
        for (int off = 32; off > 0; off >>= 1) v += __shfl_down(v, off, 64);
        if (lane == 0) red[wid][b] = v;
    }
    __syncthreads();
    if (tid < 8) {
        float ssum = 0.f;
#pragma unroll
        for (int w = 0; w < NWAVE; w++) ssum += red[w][tid];
        atomicAdd(&out[tid], ssum);
    }
}

static inline int cdiv(int a, int b) { return (a + b - 1) / b; }

extern "C" void kernel_launch(void* const* d_in, const int* in_sizes, int n_in,
                              void* d_out, int out_size, void* d_ws, size_t ws_size,
                              hipStream_t stream) {
    const int B = out_size;  // expected 8 (kernel hard-codes 8 batch accumulators)
    const int NB = in_sizes[2], NA = in_sizes[5], NT = in_sizes[10],
              NI = in_sizes[14], NC = in_sizes[19];
    const int N = in_sizes[0] / (3 * B);

    const float* coords = (const float*)d_in[0];
    const int*   bidx = (const int*)d_in[1];
    const float* br0  = (const float*)d_in[2];
    const float* bk   = (const float*)d_in[3];
    const int*   aidx = (const int*)d_in[4];
    const float* ak   = (const float*)d_in[5];
    const float* ac0  = (const float*)d_in[6];
    const float* ac1  = (const float*)d_in[7];
    const float* ac2  = (const float*)d_in[8];
    const int*   tidx = (const int*)d_in[9];
    const float* tk   = (const float*)d_in[10];
    const int*   tord = (const int*)d_in[11];
    const float* tcos = (const float*)d_in[12];
    const int*   iidx = (const int*)d_in[13];
    const float* ik   = (const float*)d_in[14];
    const float* ic0  = (const float*)d_in[15];
    const float* ic1  = (const float*)d_in[16];
    const float* ic2  = (const float*)d_in[17];
    const int*   nidx = (const int*)d_in[18];
    const float* vmin = (const float*)d_in[19];
    const float* vdep = (const float*)d_in[20];
    const float* vthr = (const float*)d_in[21];

    hipMemsetAsync(d_out, 0, (size_t)out_size * sizeof(float), stream);

    const bool use_ws = ws_size >= (size_t)N * 8 * sizeof(float4);
    float4* cw = (float4*)d_ws;
    if (use_ws) {
        transpose_coords<<<cdiv(N, TPB), TPB, 0, stream>>>(coords, cw, N);
    }

    SegInfo s;
    s.NB = NB; s.NA = NA; s.NT = NT; s.NI = NI; s.NC = NC; s.N = N;
    s.gb = cdiv(NB, TPB);
    s.ga = s.gb + cdiv(NA, TPB);
    s.gt = s.ga + cdiv(NT, TPB);
    s.gi = s.gt + cdiv(NI, TPB);
    const int total = s.gi + cdiv(NC, TPB);

    if (use_ws) {
        uff_kernel<true><<<total, TPB, 0, stream>>>(
            coords, cw, bidx, br0, bk, aidx, ak, ac0, ac1, ac2,
            tidx, tk, tord, tcos, iidx, ik, ic0, ic1, ic2,
            nidx, vmin, vdep, vthr, (float*)d_out, s);
    } else {
        uff_kernel<false><<<total, TPB, 0, stream>>>(
            coords, cw, bidx, br0, bk, aidx, ak, ac0, ac1, ac2,
            tidx, tk, tord, tcos, iidx, ik, ic0, ic1, ic2,
            nidx, vmin, vdep, vthr, (float*)d_out, s);
    }
}